// Round 14
// baseline (1897.801 us; speedup 1.0000x reference)
//
#include <hip/hip_runtime.h>
#include <hip/hip_cooperative_groups.h>
#include <math.h>

namespace cg = cooperative_groups;

#define N_NODES 40000
#define N_EDGES 640000
#define IN_F 256
#define H_F 128
#define C_F 64
#define L_LAYERS 4
#define SCAN_BLKS 157    // ceil(40000/256)
#define N_CHUNKS 64
#define CHUNK_E 10000    // N_EDGES / N_CHUNKS
#define HIST_WORDS 10000 // N_NODES / 4 (4x8-bit packed counters per word)
#define XPAD 264         // 256 + 8 bf16 pad (LDS row stride for x tile)
#define COOP_BLKS 1536   // 6 blocks/CU x 256 CUs
#define COOP_WAVES (COOP_BLKS * 4)

typedef short short8 __attribute__((ext_vector_type(8)));
typedef unsigned short ushort8 __attribute__((ext_vector_type(8)));
typedef float f32x4 __attribute__((ext_vector_type(4)));

__device__ inline short to_bf16(float f) {
    unsigned u = __builtin_bit_cast(unsigned, f);
    unsigned r = (u + 0x7FFFu + ((u >> 16) & 1u)) >> 16;
    return (short)r;
}
__device__ inline float bf16_to_f(unsigned short u) {
    unsigned v = ((unsigned)u) << 16;
    return __builtin_bit_cast(float, v);
}

// 256-thread block exclusive scan; returns excl; *tot = block total
__device__ inline int block_excl_scan(int v, int* wsum, int* tot) {
    int tid = threadIdx.x;
    int lane = tid & 63, wid = tid >> 6;
    int incl = v;
    #pragma unroll
    for (int off = 1; off < 64; off <<= 1) {
        int t = __shfl_up(incl, off, 64);
        if (lane >= off) incl += t;
    }
    if (lane == 63) wsum[wid] = incl;
    __syncthreads();
    int prefix = 0, total = 0;
    #pragma unroll
    for (int w = 0; w < 4; w++) {
        int s = wsum[w];
        if (w < wid) prefix += s;
        total += s;
    }
    *tot = total;
    return prefix + incl - v;
}

// ---------------- K0: fc1 weight transpose+bf16 ----------------
__global__ __launch_bounds__(256) void prep_fc1w(const float* __restrict__ fc1_w,
                                                 short* __restrict__ fc1_wT) {
    int i = blockIdx.x * 256 + threadIdx.x;
    int n = i >> 8, k = i & 255;
    fc1_wT[i] = to_bf16(fc1_w[k * H_F + n]);
}

// ---------------- K1: hist (LDS) || fc1 MFMA || Wcat/fc2 weight prep -----------
__global__ __launch_bounds__(256) void hist_fc1_prep(const int* __restrict__ src,
                                                     const int* __restrict__ dst,
                                                     int* __restrict__ chunk_dst,
                                                     int* __restrict__ chunk_src,
                                                     unsigned char* __restrict__ lrank8,
                                                     const float* __restrict__ x,
                                                     const short* __restrict__ wT,
                                                     const float* __restrict__ b,
                                                     unsigned short* __restrict__ h0b,
                                                     const float* __restrict__ W1,
                                                     const float* __restrict__ W2,
                                                     const float* __restrict__ fc2_w,
                                                     float s0, float s1, float s2, float s3,
                                                     short* __restrict__ WcatT,
                                                     short* __restrict__ fc2_wT) {
    __shared__ union {
        int cntp[HIST_WORDS];
        unsigned short xL[64 * XPAD];
    } sh;
    int blk = blockIdx.x;
    int tid = threadIdx.x;
    if (blk < 128) {
        int role_dst = (blk < 64);
        int w = role_dst ? blk : blk - 64;
        const int* idx = role_dst ? dst : src;
        int base = w * CHUNK_E;
        for (int i = tid; i < HIST_WORDS; i += 256) sh.cntp[i] = 0;
        __syncthreads();
        if (role_dst) {
            for (int i = tid; i < CHUNK_E; i += 256) {
                int d = idx[base + i];
                int shf = (d & 3) * 8;
                int old = atomicAdd(&sh.cntp[d >> 2], 1 << shf);
                lrank8[base + i] = (unsigned char)((old >> shf) & 0xff);
            }
        } else {
            for (int i = tid; i < CHUNK_E; i += 256) {
                int s = idx[base + i];
                atomicAdd(&sh.cntp[s >> 2], 1 << ((s & 3) * 8));
            }
        }
        __syncthreads();
        int* outp = role_dst ? (chunk_dst + w * HIST_WORDS) : (chunk_src + w * HIST_WORDS);
        for (int i = tid; i < HIST_WORDS; i += 256) outp[i] = sh.cntp[i];
        return;
    }
    if (blk >= 753) {
        int i = (blk - 753) * 256 + tid;
        if (i < 4 * 128 * 256) {
            int l = i >> 15; int r = i & 32767; int n = r >> 8; int k = r & 255;
            float sc = (l == 0) ? s0 : (l == 1) ? s1 : (l == 2) ? s2 : s3;
            float w = (k < 128) ? W1[l * 16384 + k * H_F + n]
                                : W2[l * 16384 + (k - 128) * H_F + n];
            WcatT[i] = to_bf16(sc * w);
        }
        if (i < 64 * 128) {
            int n = i >> 7, k = i & 127;
            fc2_wT[i] = to_bf16(fc2_w[k * C_F + n]);
        }
        return;
    }
    // ---- fc1 role ----
    int bb = blk - 128;
    const float* xblk = x + (size_t)bb * 64 * IN_F;
    #pragma unroll
    for (int half = 0; half < 2; half++) {
        float4 v[8];
        #pragma unroll
        for (int s = 0; s < 8; s++)
            v[s] = *(const float4*)(xblk + (half * 8 + s) * 1024 + tid * 4);
        #pragma unroll
        for (int s = 0; s < 8; s++) {
            int i = (half * 8 + s) * 1024 + tid * 4;
            int rr = i >> 8, cc = i & 255;
            unsigned p0 = (unsigned)(unsigned short)to_bf16(v[s].x)
                        | ((unsigned)(unsigned short)to_bf16(v[s].y) << 16);
            unsigned p1 = (unsigned)(unsigned short)to_bf16(v[s].z)
                        | ((unsigned)(unsigned short)to_bf16(v[s].w) << 16);
            uint2 pk = {p0, p1};
            *(uint2*)(sh.xL + rr * XPAD + cc) = pk;
        }
    }
    __syncthreads();
    int wave = tid >> 6, lane = tid & 63;
    int m = lane & 15, quad = lane >> 4;
    const unsigned short* xr = sh.xL + (wave * 16 + m) * XPAD + quad * 8;
    short8 afrag[8];
    #pragma unroll
    for (int ks = 0; ks < 8; ks++) {
        afrag[ks] = __builtin_bit_cast(short8, *(const ushort8*)(xr + ks * 32));
    }
    #pragma unroll
    for (int c = 0; c < 8; c += 2) {
        f32x4 acc0 = {0.f, 0.f, 0.f, 0.f};
        f32x4 acc1 = {0.f, 0.f, 0.f, 0.f};
        const short* b0p = wT + (size_t)(c * 16 + m) * IN_F + quad * 8;
        const short* b1p = b0p + 16 * IN_F;
        #pragma unroll
        for (int ks = 0; ks < 8; ks++) {
            short8 b0 = *(const short8*)(b0p + ks * 32);
            short8 b1 = *(const short8*)(b1p + ks * 32);
            acc0 = __builtin_amdgcn_mfma_f32_16x16x32_bf16(afrag[ks], b0, acc0, 0, 0, 0);
            acc1 = __builtin_amdgcn_mfma_f32_16x16x32_bf16(afrag[ks], b1, acc1, 0, 0, 0);
        }
        int col0 = c * 16 + m;
        int rbase = bb * 64 + wave * 16 + quad * 4;
        float bg0 = b[col0], bg1 = b[col0 + 16];
        #pragma unroll
        for (int r = 0; r < 4; r++) {
            size_t idx2 = (size_t)(rbase + r) * H_F + col0;
            float v0 = acc0[r] + bg0;
            float v1 = acc1[r] + bg1;
            v0 = v0 > 0.f ? v0 : 0.f;
            v1 = v1 > 0.f ? v1 : 0.f;
            h0b[idx2] = (unsigned short)to_bf16(v0);
            h0b[idx2 + 16] = (unsigned short)to_bf16(v1);
        }
    }
}

// ---------------- K2: per-node scan ----------------
__global__ __launch_bounds__(256) void scan1(const int* __restrict__ chunk_dst,
                                             const int* __restrict__ chunk_src,
                                             int* __restrict__ base32,
                                             float* __restrict__ rsq_in,
                                             float* __restrict__ rsq_out,
                                             float* __restrict__ sq_out,
                                             int* __restrict__ row_local,
                                             int* __restrict__ blk_sum) {
    __shared__ int wsum[4];
    int sb = blockIdx.x;
    int n = sb * 256 + threadIdx.x;
    int deg = 0, word = 0, sh = 0;
    if (n < N_NODES) {
        word = n >> 2; sh = (n & 3) * 8;
        #pragma unroll 4
        for (int w = 0; w < N_CHUNKS; w++)
            deg += (chunk_dst[w * HIST_WORDS + word] >> sh) & 0xff;
    }
    int tot;
    int excl = block_excl_scan(deg, wsum, &tot);
    if (n < N_NODES) {
        row_local[n] = excl;
        int run = excl;
        #pragma unroll 4
        for (int w = 0; w < N_CHUNKS; w++) {
            int v = (chunk_dst[w * HIST_WORDS + word] >> sh) & 0xff;
            base32[(size_t)w * N_NODES + n] = run;
            run += v;
        }
        int so = 0;
        #pragma unroll 4
        for (int w = 0; w < N_CHUNKS; w++)
            so += (chunk_src[w * HIST_WORDS + word] >> sh) & 0xff;
        float fd = (float)(deg < 1 ? 1 : deg);
        float fs = (float)(so < 1 ? 1 : so);
        rsq_in[n] = 1.0f / sqrtf(fd);
        rsq_out[n] = 1.0f / sqrtf(fs);
        sq_out[n] = sqrtf(fs);
    }
    if (threadIdx.x == 0) blk_sum[sb] = tot;
}

// ---------------- K3: CSR col fill + row_ptr + h0 scaling ----------------------
__global__ __launch_bounds__(256) void fill_fused(const int* __restrict__ src,
                                                  const int* __restrict__ dst,
                                                  const unsigned char* __restrict__ lrank8,
                                                  const int* __restrict__ base32,
                                                  const int* __restrict__ row_local,
                                                  const int* __restrict__ blk_sum,
                                                  unsigned short* __restrict__ col16,
                                                  int* __restrict__ row_ptr,
                                                  const unsigned short* __restrict__ h0b,
                                                  const float* __restrict__ rsq_out,
                                                  unsigned short* __restrict__ h0s) {
    __shared__ int wsum[4];
    __shared__ int blk_offL[SCAN_BLKS];
    int tid = threadIdx.x;
    {
        int v = (tid < SCAN_BLKS) ? blk_sum[tid] : 0;
        int tot;
        int excl = block_excl_scan(v, wsum, &tot);
        if (tid < SCAN_BLKS) blk_offL[tid] = excl;
    }
    __syncthreads();

    int blk = blockIdx.x;
    if (blk < 2500) {
        int e = blk * 256 + tid;
        int w = e / CHUNK_E;
        int s = src[e], d = dst[e];
        int rp = blk_offL[d >> 8] + base32[(size_t)w * N_NODES + d] + (int)lrank8[e];
        col16[rp] = (unsigned short)s;
        return;
    }
    if (blk < 2657) {
        int n = (blk - 2500) * 256 + tid;
        if (n < N_NODES) row_ptr[n] = blk_offL[n >> 8] + row_local[n];
        if (blk == 2500 && tid == 0) row_ptr[N_NODES] = N_EDGES;
        return;
    }
    int j = (blk - 2657) * 2048 + tid * 8;
    ushort8 u = *(const ushort8*)(h0b + j);
    float rs = rsq_out[j >> 7];
    ushort8 o;
    #pragma unroll
    for (int jj = 0; jj < 8; jj++) o[jj] = (unsigned short)to_bf16(rs * bf16_to_f(u[jj]));
    *(ushort8*)(h0s + j) = o;
}

// ================= shared device bodies for the layer chain ====================
__device__ __forceinline__ void spmm_node(int n,
                                          const unsigned short* __restrict__ hs,
                                          const int* __restrict__ row_ptr,
                                          const unsigned short* __restrict__ col16,
                                          const float* __restrict__ rsq_in,
                                          unsigned short* __restrict__ aggb,
                                          int slot, int fi) {
    int e0 = row_ptr[n], e1 = row_ptr[n + 1];
    float a[8] = {};
    for (int e = e0 + slot; e < e1; e += 16) {
        int eb = e + 4, ec = e + 8, ed = e + 12;
        int c0 = col16[e];
        int c1 = (eb < e1) ? col16[eb] : c0;  float w1 = (eb < e1) ? 1.f : 0.f;
        int c2 = (ec < e1) ? col16[ec] : c0;  float w2 = (ec < e1) ? 1.f : 0.f;
        int c3 = (ed < e1) ? col16[ed] : c0;  float w3 = (ed < e1) ? 1.f : 0.f;
        ushort8 u0 = *(const ushort8*)(hs + (size_t)c0 * H_F + fi * 8);
        ushort8 u1 = *(const ushort8*)(hs + (size_t)c1 * H_F + fi * 8);
        ushort8 u2 = *(const ushort8*)(hs + (size_t)c2 * H_F + fi * 8);
        ushort8 u3 = *(const ushort8*)(hs + (size_t)c3 * H_F + fi * 8);
        #pragma unroll
        for (int j = 0; j < 8; j++) {
            a[j] += bf16_to_f(u0[j]) + w1 * bf16_to_f(u1[j])
                  + w2 * bf16_to_f(u2[j]) + w3 * bf16_to_f(u3[j]);
        }
    }
    #pragma unroll
    for (int mask = 16; mask <= 32; mask <<= 1) {
        #pragma unroll
        for (int j = 0; j < 8; j++) a[j] += __shfl_xor(a[j], mask, 64);
    }
    if (slot == 0) {
        float rs = rsq_in[n];
        ushort8 r;
        #pragma unroll
        for (int j = 0; j < 8; j++) r[j] = (unsigned short)to_bf16(rs * a[j]);
        *(ushort8*)(aggb + (size_t)n * H_F + fi * 8) = r;
    }
}

__device__ __forceinline__ void combine_tile(int t,
                                             const unsigned short* __restrict__ aggb,
                                             const unsigned short* __restrict__ h0b,
                                             const unsigned short* __restrict__ hs_in,
                                             const short* __restrict__ wT,
                                             const float* __restrict__ bgc,
                                             const float* __restrict__ rsq_out,
                                             const float* __restrict__ sq_out,
                                             float omb5,
                                             unsigned short* __restrict__ hs_out) {
    int tid = threadIdx.x;
    int wave = tid >> 6, lane = tid & 63;
    int rowgrp = wave >> 1, chalf = wave & 1;
    int m = lane & 15, quad = lane >> 4;
    int row = t * 32 + rowgrp * 16 + m;
    const unsigned short* aggr = aggb + (size_t)row * H_F + quad * 8;
    const unsigned short* h0r  = h0b + (size_t)row * H_F + quad * 8;
    short8 afrag[8];
    #pragma unroll
    for (int ks = 0; ks < 4; ks++) {
        afrag[ks] = __builtin_bit_cast(short8, *(const ushort8*)(aggr + ks * 32));
        afrag[ks + 4] = __builtin_bit_cast(short8, *(const ushort8*)(h0r + ks * 32));
    }
    #pragma unroll
    for (int ci = 0; ci < 4; ci += 2) {
        int c = chalf * 4 + ci;
        f32x4 acc0 = {0.f, 0.f, 0.f, 0.f};
        f32x4 acc1 = {0.f, 0.f, 0.f, 0.f};
        const short* b0p = wT + (size_t)(c * 16 + m) * 256 + quad * 8;
        const short* b1p = b0p + 16 * 256;
        #pragma unroll
        for (int ks = 0; ks < 8; ks++) {
            short8 b0 = *(const short8*)(b0p + ks * 32);
            short8 b1 = *(const short8*)(b1p + ks * 32);
            acc0 = __builtin_amdgcn_mfma_f32_16x16x32_bf16(afrag[ks], b0, acc0, 0, 0, 0);
            acc1 = __builtin_amdgcn_mfma_f32_16x16x32_bf16(afrag[ks], b1, acc1, 0, 0, 0);
        }
        int col0 = c * 16 + m;
        int rbase = t * 32 + rowgrp * 16 + quad * 4;
        float bg0 = bgc[col0], bg1 = bgc[col0 + 16];
        #pragma unroll
        for (int r = 0; r < 4; r++) {
            int rw = rbase + r;
            size_t idx = (size_t)rw * H_F + col0;
            float sq = sq_out[rw];
            float rsq = rsq_out[rw];
            float s0 = bf16_to_f(aggb[idx]) + bf16_to_f(h0b[idx]);
            float s1 = bf16_to_f(aggb[idx + 16]) + bf16_to_f(h0b[idx + 16]);
            float v0 = omb5 * s0 + acc0[r] + bg0 + sq * bf16_to_f(hs_in[idx]);
            float v1 = omb5 * s1 + acc1[r] + bg1 + sq * bf16_to_f(hs_in[idx + 16]);
            v0 = v0 > 0.f ? v0 : 0.f;
            v1 = v1 > 0.f ? v1 : 0.f;
            hs_out[idx] = (unsigned short)to_bf16(rsq * v0);
            hs_out[idx + 16] = (unsigned short)to_bf16(rsq * v1);
        }
    }
}

__device__ __forceinline__ void fc2_tile(int t,
                                         const unsigned short* __restrict__ hs,
                                         const float* __restrict__ sq_out,
                                         const short* __restrict__ wT,
                                         const float* __restrict__ b,
                                         float* __restrict__ out) {
    int tid = threadIdx.x;
    int wave = tid >> 6, lane = tid & 63;
    int m = lane & 15, quad = lane >> 4;
    int row = t * 64 + wave * 16 + m;
    const unsigned short* hr = hs + (size_t)row * H_F + quad * 8;
    float sq = sq_out[row];
    short8 afrag[4];
    #pragma unroll
    for (int ks = 0; ks < 4; ks++) {
        ushort8 u = *(const ushort8*)(hr + ks * 32);
        #pragma unroll
        for (int j = 0; j < 8; j++) afrag[ks][j] = to_bf16(sq * bf16_to_f(u[j]));
    }
    #pragma unroll
    for (int c = 0; c < 4; c += 2) {
        f32x4 acc0 = {0.f, 0.f, 0.f, 0.f};
        f32x4 acc1 = {0.f, 0.f, 0.f, 0.f};
        const short* b0p = wT + (size_t)(c * 16 + m) * H_F + quad * 8;
        const short* b1p = b0p + 16 * H_F;
        #pragma unroll
        for (int ks = 0; ks < 4; ks++) {
            short8 b0 = *(const short8*)(b0p + ks * 32);
            short8 b1 = *(const short8*)(b1p + ks * 32);
            acc0 = __builtin_amdgcn_mfma_f32_16x16x32_bf16(afrag[ks], b0, acc0, 0, 0, 0);
            acc1 = __builtin_amdgcn_mfma_f32_16x16x32_bf16(afrag[ks], b1, acc1, 0, 0, 0);
        }
        int col0 = c * 16 + m;
        int rbase = t * 64 + wave * 16 + quad * 4;
        float bg0 = b[col0], bg1 = b[col0 + 16];
        #pragma unroll
        for (int r = 0; r < 4; r++) {
            size_t idx = (size_t)(rbase + r) * C_F + col0;
            out[idx] = acc0[r] + bg0;
            out[idx + 16] = acc1[r] + bg1;
        }
    }
}

// ---------------- cooperative mega-kernel: 4x(spmm, combine) + fc2 -------------
__global__ __launch_bounds__(256, 6) void layers_coop(const unsigned short* h0s,
                                                      unsigned short* hAs,
                                                      unsigned short* hBs,
                                                      const unsigned short* h0b,
                                                      const int* row_ptr,
                                                      const unsigned short* col16,
                                                      const float* rsq_in,
                                                      const float* rsq_out,
                                                      const float* sq_out,
                                                      unsigned short* aggb,
                                                      const short* WcatT,
                                                      const float* bgc,
                                                      float4 omb,
                                                      const short* fc2_wT,
                                                      const float* fc2_b,
                                                      float* out) {
    cg::grid_group grid = cg::this_grid();
    const unsigned short* sp_in[4] = {h0s, hAs, hBs, hAs};
    unsigned short* out_b[4]       = {hAs, hBs, hAs, hBs};
    float omb5[4] = {omb.x, omb.y, omb.z, omb.w};
    int wave = threadIdx.x >> 6, lane = threadIdx.x & 63;
    int slot = lane >> 4, fi = lane & 15;
    int gw = blockIdx.x * 4 + wave;
    for (int l = 0; l < L_LAYERS; l++) {
        for (int n = gw; n < N_NODES; n += COOP_WAVES)
            spmm_node(n, sp_in[l], row_ptr, col16, rsq_in, aggb, slot, fi);
        grid.sync();
        if (blockIdx.x < N_NODES / 32)
            combine_tile(blockIdx.x, aggb, h0b, sp_in[l],
                         WcatT + (size_t)l * 128 * 256, bgc + (size_t)l * H_F,
                         rsq_out, sq_out, omb5[l], out_b[l]);
        grid.sync();
    }
    if (blockIdx.x < N_NODES / 64)
        fc2_tile(blockIdx.x, hBs, sq_out, fc2_wT, fc2_b, out);
}

// ---------------- fallback split kernels (same device bodies) ------------------
__global__ __launch_bounds__(256) void spmm_kernel(const unsigned short* __restrict__ hs,
                                                   const int* __restrict__ row_ptr,
                                                   const unsigned short* __restrict__ col16,
                                                   const float* __restrict__ rsq_in,
                                                   unsigned short* __restrict__ aggb) {
    int wave = threadIdx.x >> 6, lane = threadIdx.x & 63;
    spmm_node(blockIdx.x * 4 + wave, hs, row_ptr, col16, rsq_in, aggb,
              lane >> 4, lane & 15);
}

__global__ __launch_bounds__(256) void combine_mfma(const unsigned short* __restrict__ aggb,
                                                    const unsigned short* __restrict__ h0b,
                                                    const unsigned short* __restrict__ hs_in,
                                                    const short* __restrict__ wT,
                                                    const float* __restrict__ bgc,
                                                    const float* __restrict__ rsq_out,
                                                    const float* __restrict__ sq_out,
                                                    float omb5,
                                                    unsigned short* __restrict__ hs_out) {
    combine_tile(blockIdx.x, aggb, h0b, hs_in, wT, bgc, rsq_out, sq_out, omb5, hs_out);
}

__global__ __launch_bounds__(256) void fc2_mfma(const unsigned short* __restrict__ hs,
                                                const float* __restrict__ sq_out,
                                                const short* __restrict__ wT,
                                                const float* __restrict__ b,
                                                float* __restrict__ out) {
    fc2_tile(blockIdx.x, hs, sq_out, wT, b, out);
}

extern "C" void kernel_launch(void* const* d_in, const int* in_sizes, int n_in,
                              void* d_out, int out_size, void* d_ws, size_t ws_size,
                              hipStream_t stream) {
    const float* x     = (const float*)d_in[0];
    const float* fc1_w = (const float*)d_in[1];
    const float* fc1_b = (const float*)d_in[2];
    const float* W1    = (const float*)d_in[3];
    const float* W2    = (const float*)d_in[4];
    const float* bgc   = (const float*)d_in[5];
    const float* fc2_w = (const float*)d_in[6];
    const float* fc2_b = (const float*)d_in[7];
    const int*   src   = (const int*)d_in[8];
    const int*   dst   = (const int*)d_in[9];
    float* out = (float*)d_out;

    char* p = (char*)d_ws;
    auto alloc = [&](size_t bytes) {
        char* r = p;
        p += (bytes + 255) & ~(size_t)255;
        return r;
    };
    int*   chunk_dst = (int*)alloc((size_t)N_CHUNKS * HIST_WORDS * 4);
    int*   chunk_src = (int*)alloc((size_t)N_CHUNKS * HIST_WORDS * 4);
    int*   base32    = (int*)alloc((size_t)N_CHUNKS * N_NODES * 4);
    unsigned char* lrank8 = (unsigned char*)alloc((size_t)N_EDGES);
    float* rsq_in  = (float*)alloc((size_t)N_NODES * 4);
    float* rsq_out = (float*)alloc((size_t)N_NODES * 4);
    float* sq_out  = (float*)alloc((size_t)N_NODES * 4);
    int*   row_ptr   = (int*)alloc((size_t)(N_NODES + 1) * 4);
    int*   row_local = (int*)alloc((size_t)N_NODES * 4);
    int*   blk_sum   = (int*)alloc((size_t)SCAN_BLKS * 4);
    unsigned short* col16 = (unsigned short*)alloc((size_t)N_EDGES * 2);
    unsigned short* aggb = (unsigned short*)alloc((size_t)N_NODES * H_F * 2);
    unsigned short* h0b  = (unsigned short*)alloc((size_t)N_NODES * H_F * 2);
    unsigned short* h0s  = (unsigned short*)alloc((size_t)N_NODES * H_F * 2);
    unsigned short* hAs  = (unsigned short*)alloc((size_t)N_NODES * H_F * 2);
    unsigned short* hBs  = (unsigned short*)alloc((size_t)N_NODES * H_F * 2);
    short* fc1_wT  = (short*)alloc((size_t)128 * 256 * 2);
    short* WcatT   = (short*)alloc((size_t)4 * 128 * 256 * 2);
    short* fc2_wT  = (short*)alloc((size_t)64 * 128 * 2);

    float beta[4], wscale[4];
    float4 omb;
    float* ombp = &omb.x;
    for (int l = 0; l < 4; l++) {
        beta[l] = (float)log(1.0 / (double)(l + 1) + 1.0);
        wscale[l] = 0.5f * beta[l];
        ombp[l] = 0.5f * (1.f - beta[l]);
    }

    prep_fc1w<<<128, 256, 0, stream>>>(fc1_w, fc1_wT);
    hist_fc1_prep<<<1265, 256, 0, stream>>>(src, dst, chunk_dst, chunk_src, lrank8,
                                            x, fc1_wT, fc1_b, h0b,
                                            W1, W2, fc2_w,
                                            wscale[0], wscale[1], wscale[2], wscale[3],
                                            WcatT, fc2_wT);
    scan1<<<SCAN_BLKS, 256, 0, stream>>>(chunk_dst, chunk_src, base32,
                                         rsq_in, rsq_out, sq_out, row_local, blk_sum);
    fill_fused<<<5157, 256, 0, stream>>>(src, dst, lrank8, base32, row_local, blk_sum,
                                         col16, row_ptr, h0b, rsq_out, h0s);

    // ---- cooperative layer chain (fallback: split dispatches) ----
    const unsigned short* h0s_c = h0s;
    const unsigned short* h0b_c = h0b;
    const int* row_ptr_c = row_ptr;
    const unsigned short* col16_c = col16;
    const float* rsq_in_c = rsq_in;
    const float* rsq_out_c = rsq_out;
    const float* sq_out_c = sq_out;
    const short* WcatT_c = WcatT;
    const short* fc2_wT_c = fc2_wT;
    void* args[] = {(void*)&h0s_c, (void*)&hAs, (void*)&hBs, (void*)&h0b_c,
                    (void*)&row_ptr_c, (void*)&col16_c, (void*)&rsq_in_c,
                    (void*)&rsq_out_c, (void*)&sq_out_c, (void*)&aggb,
                    (void*)&WcatT_c, (void*)&bgc, (void*)&omb,
                    (void*)&fc2_wT_c, (void*)&fc2_b, (void*)&out};
    hipError_t cerr = hipLaunchCooperativeKernel((const void*)layers_coop,
                                                 dim3(COOP_BLKS), dim3(256),
                                                 args, 0, stream);
    if (cerr != hipSuccess) {
        (void)hipGetLastError();
        const unsigned short* sp_in[4] = {h0s, hAs, hBs, hAs};
        unsigned short* out_b[4]       = {hAs, hBs, hAs, hBs};
        for (int l = 0; l < L_LAYERS; l++) {
            spmm_kernel<<<N_NODES / 4, 256, 0, stream>>>(sp_in[l], row_ptr, col16,
                                                         rsq_in, aggb);
            combine_mfma<<<N_NODES / 32, 256, 0, stream>>>(aggb, h0b, sp_in[l],
                                                           WcatT + (size_t)l * 128 * 256,
                                                           bgc + (size_t)l * H_F,
                                                           rsq_out, sq_out, ombp[l],
                                                           out_b[l]);
        }
        fc2_mfma<<<N_NODES / 64, 256, 0, stream>>>(hBs, sq_out, fc2_wT, fc2_b, out);
    }
}

// Round 15
// 358.844 us; speedup vs baseline: 5.2887x; 5.2887x over previous
//
#include <hip/hip_runtime.h>
#include <math.h>

#define N_NODES 40000
#define N_EDGES 640000
#define IN_F 256
#define H_F 128
#define C_F 64
#define L_LAYERS 4
#define SCAN_BLKS 157    // ceil(40000/256)
#define N_CHUNKS 64
#define CHUNK_E 10000    // N_EDGES / N_CHUNKS
#define HIST_WORDS 10000 // N_NODES / 4 (4x8-bit packed counters per word)
#define XPAD 264         // 256 + 8 bf16 pad (LDS row stride for x tile)
#define LPAD 132         // 128 + 4 bf16 pad (LDS row stride for agg/v tiles)

typedef short short8 __attribute__((ext_vector_type(8)));
typedef unsigned short ushort8 __attribute__((ext_vector_type(8)));
typedef float f32x4 __attribute__((ext_vector_type(4)));

__device__ inline short to_bf16(float f) {
    unsigned u = __builtin_bit_cast(unsigned, f);
    unsigned r = (u + 0x7FFFu + ((u >> 16) & 1u)) >> 16;
    return (short)r;
}
__device__ inline float bf16_to_f(unsigned short u) {
    unsigned v = ((unsigned)u) << 16;
    return __builtin_bit_cast(float, v);
}

// 256-thread block exclusive scan; returns excl; *tot = block total
__device__ inline int block_excl_scan(int v, int* wsum, int* tot) {
    int tid = threadIdx.x;
    int lane = tid & 63, wid = tid >> 6;
    int incl = v;
    #pragma unroll
    for (int off = 1; off < 64; off <<= 1) {
        int t = __shfl_up(incl, off, 64);
        if (lane >= off) incl += t;
    }
    if (lane == 63) wsum[wid] = incl;
    __syncthreads();
    int prefix = 0, total = 0;
    #pragma unroll
    for (int w = 0; w < 4; w++) {
        int s = wsum[w];
        if (w < wid) prefix += s;
        total += s;
    }
    *tot = total;
    return prefix + incl - v;
}

// ---------------- K0: fc1 weight transpose+bf16 ----------------
__global__ __launch_bounds__(256) void prep_fc1w(const float* __restrict__ fc1_w,
                                                 short* __restrict__ fc1_wT) {
    int i = blockIdx.x * 256 + threadIdx.x;
    int n = i >> 8, k = i & 255;
    fc1_wT[i] = to_bf16(fc1_w[k * H_F + n]);
}

// ---------------- K1: hist (LDS) || fc1 MFMA || Wcat/fc2 weight prep -----------
__global__ __launch_bounds__(256) void hist_fc1_prep(const int* __restrict__ src,
                                                     const int* __restrict__ dst,
                                                     int* __restrict__ chunk_dst,
                                                     int* __restrict__ chunk_src,
                                                     unsigned char* __restrict__ lrank8,
                                                     const float* __restrict__ x,
                                                     const short* __restrict__ wT,
                                                     const float* __restrict__ b,
                                                     unsigned short* __restrict__ h0b,
                                                     const float* __restrict__ W1,
                                                     const float* __restrict__ W2,
                                                     const float* __restrict__ fc2_w,
                                                     float s0, float s1, float s2, float s3,
                                                     short* __restrict__ WcatT,
                                                     short* __restrict__ fc2_wT) {
    __shared__ union {
        int cntp[HIST_WORDS];
        unsigned short xL[64 * XPAD];
    } sh;
    int blk = blockIdx.x;
    int tid = threadIdx.x;
    if (blk < 128) {
        int role_dst = (blk < 64);
        int w = role_dst ? blk : blk - 64;
        const int* idx = role_dst ? dst : src;
        int base = w * CHUNK_E;
        for (int i = tid; i < HIST_WORDS; i += 256) sh.cntp[i] = 0;
        __syncthreads();
        if (role_dst) {
            for (int i = tid; i < CHUNK_E; i += 256) {
                int d = idx[base + i];
                int shf = (d & 3) * 8;
                int old = atomicAdd(&sh.cntp[d >> 2], 1 << shf);
                lrank8[base + i] = (unsigned char)((old >> shf) & 0xff);
            }
        } else {
            for (int i = tid; i < CHUNK_E; i += 256) {
                int s = idx[base + i];
                atomicAdd(&sh.cntp[s >> 2], 1 << ((s & 3) * 8));
            }
        }
        __syncthreads();
        int* outp = role_dst ? (chunk_dst + w * HIST_WORDS) : (chunk_src + w * HIST_WORDS);
        for (int i = tid; i < HIST_WORDS; i += 256) outp[i] = sh.cntp[i];
        return;
    }
    if (blk >= 753) {
        int i = (blk - 753) * 256 + tid;
        if (i < 4 * 128 * 256) {
            int l = i >> 15; int r = i & 32767; int n = r >> 8; int k = r & 255;
            float sc = (l == 0) ? s0 : (l == 1) ? s1 : (l == 2) ? s2 : s3;
            float w = (k < 128) ? W1[l * 16384 + k * H_F + n]
                                : W2[l * 16384 + (k - 128) * H_F + n];
            WcatT[i] = to_bf16(sc * w);
        }
        if (i < 64 * 128) {
            int n = i >> 7, k = i & 127;
            fc2_wT[i] = to_bf16(fc2_w[k * C_F + n]);
        }
        return;
    }
    // ---- fc1 role ----
    int bb = blk - 128;
    const float* xblk = x + (size_t)bb * 64 * IN_F;
    #pragma unroll
    for (int half = 0; half < 2; half++) {
        float4 v[8];
        #pragma unroll
        for (int s = 0; s < 8; s++)
            v[s] = *(const float4*)(xblk + (half * 8 + s) * 1024 + tid * 4);
        #pragma unroll
        for (int s = 0; s < 8; s++) {
            int i = (half * 8 + s) * 1024 + tid * 4;
            int rr = i >> 8, cc = i & 255;
            unsigned p0 = (unsigned)(unsigned short)to_bf16(v[s].x)
                        | ((unsigned)(unsigned short)to_bf16(v[s].y) << 16);
            unsigned p1 = (unsigned)(unsigned short)to_bf16(v[s].z)
                        | ((unsigned)(unsigned short)to_bf16(v[s].w) << 16);
            uint2 pk = {p0, p1};
            *(uint2*)(sh.xL + rr * XPAD + cc) = pk;
        }
    }
    __syncthreads();
    int wave = tid >> 6, lane = tid & 63;
    int m = lane & 15, quad = lane >> 4;
    const unsigned short* xr = sh.xL + (wave * 16 + m) * XPAD + quad * 8;
    short8 afrag[8];
    #pragma unroll
    for (int ks = 0; ks < 8; ks++) {
        afrag[ks] = __builtin_bit_cast(short8, *(const ushort8*)(xr + ks * 32));
    }
    #pragma unroll
    for (int c = 0; c < 8; c += 2) {
        f32x4 acc0 = {0.f, 0.f, 0.f, 0.f};
        f32x4 acc1 = {0.f, 0.f, 0.f, 0.f};
        const short* b0p = wT + (size_t)(c * 16 + m) * IN_F + quad * 8;
        const short* b1p = b0p + 16 * IN_F;
        #pragma unroll
        for (int ks = 0; ks < 8; ks++) {
            short8 b0 = *(const short8*)(b0p + ks * 32);
            short8 b1 = *(const short8*)(b1p + ks * 32);
            acc0 = __builtin_amdgcn_mfma_f32_16x16x32_bf16(afrag[ks], b0, acc0, 0, 0, 0);
            acc1 = __builtin_amdgcn_mfma_f32_16x16x32_bf16(afrag[ks], b1, acc1, 0, 0, 0);
        }
        int col0 = c * 16 + m;
        int rbase = bb * 64 + wave * 16 + quad * 4;
        float bg0 = b[col0], bg1 = b[col0 + 16];
        #pragma unroll
        for (int r = 0; r < 4; r++) {
            size_t idx2 = (size_t)(rbase + r) * H_F + col0;
            float v0 = acc0[r] + bg0;
            float v1 = acc1[r] + bg1;
            v0 = v0 > 0.f ? v0 : 0.f;
            v1 = v1 > 0.f ? v1 : 0.f;
            h0b[idx2] = (unsigned short)to_bf16(v0);
            h0b[idx2 + 16] = (unsigned short)to_bf16(v1);
        }
    }
}

// ---------------- K2: per-node scan ----------------
__global__ __launch_bounds__(256) void scan1(const int* __restrict__ chunk_dst,
                                             const int* __restrict__ chunk_src,
                                             int* __restrict__ base32,
                                             float* __restrict__ rsq_in,
                                             float* __restrict__ rsq_out,
                                             float* __restrict__ sq_out,
                                             int* __restrict__ row_local,
                                             int* __restrict__ blk_sum) {
    __shared__ int wsum[4];
    int sb = blockIdx.x;
    int n = sb * 256 + threadIdx.x;
    int deg = 0, word = 0, sh = 0;
    if (n < N_NODES) {
        word = n >> 2; sh = (n & 3) * 8;
        #pragma unroll 4
        for (int w = 0; w < N_CHUNKS; w++)
            deg += (chunk_dst[w * HIST_WORDS + word] >> sh) & 0xff;
    }
    int tot;
    int excl = block_excl_scan(deg, wsum, &tot);
    if (n < N_NODES) {
        row_local[n] = excl;
        int run = excl;
        #pragma unroll 4
        for (int w = 0; w < N_CHUNKS; w++) {
            int v = (chunk_dst[w * HIST_WORDS + word] >> sh) & 0xff;
            base32[(size_t)w * N_NODES + n] = run;
            run += v;
        }
        int so = 0;
        #pragma unroll 4
        for (int w = 0; w < N_CHUNKS; w++)
            so += (chunk_src[w * HIST_WORDS + word] >> sh) & 0xff;
        float fd = (float)(deg < 1 ? 1 : deg);
        float fs = (float)(so < 1 ? 1 : so);
        rsq_in[n] = 1.0f / sqrtf(fd);
        rsq_out[n] = 1.0f / sqrtf(fs);
        sq_out[n] = sqrtf(fs);
    }
    if (threadIdx.x == 0) blk_sum[sb] = tot;
}

// ---------------- K3: CSR col fill + row_ptr + h0 scaling ----------------------
__global__ __launch_bounds__(256) void fill_fused(const int* __restrict__ src,
                                                  const int* __restrict__ dst,
                                                  const unsigned char* __restrict__ lrank8,
                                                  const int* __restrict__ base32,
                                                  const int* __restrict__ row_local,
                                                  const int* __restrict__ blk_sum,
                                                  unsigned short* __restrict__ col16,
                                                  int* __restrict__ row_ptr,
                                                  const unsigned short* __restrict__ h0b,
                                                  const float* __restrict__ rsq_out,
                                                  unsigned short* __restrict__ h0s) {
    __shared__ int wsum[4];
    __shared__ int blk_offL[SCAN_BLKS];
    int tid = threadIdx.x;
    {
        int v = (tid < SCAN_BLKS) ? blk_sum[tid] : 0;
        int tot;
        int excl = block_excl_scan(v, wsum, &tot);
        if (tid < SCAN_BLKS) blk_offL[tid] = excl;
    }
    __syncthreads();

    int blk = blockIdx.x;
    if (blk < 2500) {
        int e = blk * 256 + tid;
        int w = e / CHUNK_E;
        int s = src[e], d = dst[e];
        int rp = blk_offL[d >> 8] + base32[(size_t)w * N_NODES + d] + (int)lrank8[e];
        col16[rp] = (unsigned short)s;
        return;
    }
    if (blk < 2657) {
        int n = (blk - 2500) * 256 + tid;
        if (n < N_NODES) row_ptr[n] = blk_offL[n >> 8] + row_local[n];
        if (blk == 2500 && tid == 0) row_ptr[N_NODES] = N_EDGES;
        return;
    }
    int j = (blk - 2657) * 2048 + tid * 8;
    ushort8 u = *(const ushort8*)(h0b + j);
    float rs = rsq_out[j >> 7];
    ushort8 o;
    #pragma unroll
    for (int jj = 0; jj < 8; jj++) o[jj] = (unsigned short)to_bf16(rs * bf16_to_f(u[jj]));
    *(ushort8*)(h0s + j) = o;
}

// ---------------- fused layer: spmm (agg -> LDS) + combine MFMA [+ fc2] --------
// block = 16 nodes, grid 2500 (10000 waves: full gather residency).
// phase1: wave handles 4 nodes, 4 slots x 16 lanes, 4-deep predicated gathers;
//         agg rounded to bf16 in LDS (bit-identical to the split aggb path).
// phase2: combine, 4-way c-split (wave w -> col groups {2w, 2w+1}).
// phase3 (last layer): fc2 from LDS v-tile, wave w -> 16-col group w.
__global__ __launch_bounds__(256) void layer_fused(const unsigned short* __restrict__ hs_in,
                                                   const unsigned short* __restrict__ h0b,
                                                   const int* __restrict__ row_ptr,
                                                   const unsigned short* __restrict__ col16,
                                                   const float* __restrict__ rsq_in,
                                                   const float* __restrict__ rsq_out,
                                                   const float* __restrict__ sq_out,
                                                   const short* __restrict__ wT,
                                                   const float* __restrict__ bgc,
                                                   float omb5,
                                                   unsigned short* __restrict__ hs_out,
                                                   const short* __restrict__ fc2_wT,
                                                   const float* __restrict__ fc2_b,
                                                   float* __restrict__ out) {
    __shared__ unsigned short aggL[16 * LPAD];
    __shared__ unsigned short vL[16 * LPAD];
    int tid = threadIdx.x;
    int wave = tid >> 6, lane = tid & 63;
    int slot = lane >> 4, fi = lane & 15;
    int nodebase = blockIdx.x * 16;

    // ---- phase 1: spmm for this wave's 4 nodes ----
    #pragma unroll
    for (int i = 0; i < 4; i++) {
        int rl = wave * 4 + i;
        int n = nodebase + rl;
        int e0 = row_ptr[n], e1 = row_ptr[n + 1];
        float a[8] = {};
        for (int e = e0 + slot; e < e1; e += 16) {
            int eb = e + 4, ec = e + 8, ed = e + 12;
            int c0 = col16[e];
            int c1 = (eb < e1) ? col16[eb] : c0;  float w1 = (eb < e1) ? 1.f : 0.f;
            int c2 = (ec < e1) ? col16[ec] : c0;  float w2 = (ec < e1) ? 1.f : 0.f;
            int c3 = (ed < e1) ? col16[ed] : c0;  float w3 = (ed < e1) ? 1.f : 0.f;
            ushort8 u0 = *(const ushort8*)(hs_in + (size_t)c0 * H_F + fi * 8);
            ushort8 u1 = *(const ushort8*)(hs_in + (size_t)c1 * H_F + fi * 8);
            ushort8 u2 = *(const ushort8*)(hs_in + (size_t)c2 * H_F + fi * 8);
            ushort8 u3 = *(const ushort8*)(hs_in + (size_t)c3 * H_F + fi * 8);
            #pragma unroll
            for (int j = 0; j < 8; j++) {
                a[j] += bf16_to_f(u0[j]) + w1 * bf16_to_f(u1[j])
                      + w2 * bf16_to_f(u2[j]) + w3 * bf16_to_f(u3[j]);
            }
        }
        #pragma unroll
        for (int mask = 16; mask <= 32; mask <<= 1) {
            #pragma unroll
            for (int j = 0; j < 8; j++) a[j] += __shfl_xor(a[j], mask, 64);
        }
        if (slot == 0) {
            float rs = rsq_in[n];
            ushort8 r;
            #pragma unroll
            for (int j = 0; j < 8; j++) r[j] = (unsigned short)to_bf16(rs * a[j]);
            *(ushort8*)(aggL + rl * LPAD + fi * 8) = r;
        }
    }
    __syncthreads();

    // ---- phase 2: combine, wave w -> col groups {2w, 2w+1} ----
    int m = lane & 15, quad = lane >> 4;
    {
        const unsigned short* aggr = aggL + m * LPAD + quad * 8;
        const unsigned short* h0r  = h0b + (size_t)(nodebase + m) * H_F + quad * 8;
        short8 afrag[8];
        #pragma unroll
        for (int ks = 0; ks < 4; ks++) {
            afrag[ks] = __builtin_bit_cast(short8, *(const ushort8*)(aggr + ks * 32));
            afrag[ks + 4] = __builtin_bit_cast(short8, *(const ushort8*)(h0r + ks * 32));
        }
        int c = wave * 2;
        f32x4 acc0 = {0.f, 0.f, 0.f, 0.f};
        f32x4 acc1 = {0.f, 0.f, 0.f, 0.f};
        const short* b0p = wT + (size_t)(c * 16 + m) * 256 + quad * 8;
        const short* b1p = b0p + 16 * 256;
        #pragma unroll
        for (int ks = 0; ks < 8; ks++) {
            short8 b0 = *(const short8*)(b0p + ks * 32);
            short8 b1 = *(const short8*)(b1p + ks * 32);
            acc0 = __builtin_amdgcn_mfma_f32_16x16x32_bf16(afrag[ks], b0, acc0, 0, 0, 0);
            acc1 = __builtin_amdgcn_mfma_f32_16x16x32_bf16(afrag[ks], b1, acc1, 0, 0, 0);
        }
        int col0 = c * 16 + m;
        float bg0 = bgc[col0], bg1 = bgc[col0 + 16];
        #pragma unroll
        for (int r = 0; r < 4; r++) {
            int rl = quad * 4 + r;
            int rw = nodebase + rl;
            size_t idx = (size_t)rw * H_F + col0;
            float sq = sq_out[rw];
            float rsq = rsq_out[rw];
            float s0 = bf16_to_f(aggL[rl * LPAD + col0]) + bf16_to_f(h0b[idx]);
            float s1 = bf16_to_f(aggL[rl * LPAD + col0 + 16]) + bf16_to_f(h0b[idx + 16]);
            float v0 = omb5 * s0 + acc0[r] + bg0 + sq * bf16_to_f(hs_in[idx]);
            float v1 = omb5 * s1 + acc1[r] + bg1 + sq * bf16_to_f(hs_in[idx + 16]);
            v0 = v0 > 0.f ? v0 : 0.f;
            v1 = v1 > 0.f ? v1 : 0.f;
            hs_out[idx] = (unsigned short)to_bf16(rsq * v0);
            hs_out[idx + 16] = (unsigned short)to_bf16(rsq * v1);
            if (out) {
                vL[rl * LPAD + col0] = (unsigned short)to_bf16(v0);
                vL[rl * LPAD + col0 + 16] = (unsigned short)to_bf16(v1);
            }
        }
    }

    // ---- phase 3 (last layer only): fc2 from LDS v-tile ----
    if (out) {
        __syncthreads();
        const unsigned short* vr = vL + m * LPAD + quad * 8;
        short8 afrag[4];
        #pragma unroll
        for (int ks = 0; ks < 4; ks++) {
            afrag[ks] = __builtin_bit_cast(short8, *(const ushort8*)(vr + ks * 32));
        }
        int c = wave;                       // 4 groups of 16 cols
        f32x4 acc = {0.f, 0.f, 0.f, 0.f};
        const short* bp = fc2_wT + (size_t)(c * 16 + m) * H_F + quad * 8;
        #pragma unroll
        for (int ks = 0; ks < 4; ks++) {
            short8 b0 = *(const short8*)(bp + ks * 32);
            acc = __builtin_amdgcn_mfma_f32_16x16x32_bf16(afrag[ks], b0, acc, 0, 0, 0);
        }
        int col0 = c * 16 + m;
        float bg = fc2_b[col0];
        #pragma unroll
        for (int r = 0; r < 4; r++) {
            int rw = nodebase + quad * 4 + r;
            out[(size_t)rw * C_F + col0] = acc[r] + bg;
        }
    }
}

extern "C" void kernel_launch(void* const* d_in, const int* in_sizes, int n_in,
                              void* d_out, int out_size, void* d_ws, size_t ws_size,
                              hipStream_t stream) {
    const float* x     = (const float*)d_in[0];
    const float* fc1_w = (const float*)d_in[1];
    const float* fc1_b = (const float*)d_in[2];
    const float* W1    = (const float*)d_in[3];
    const float* W2    = (const float*)d_in[4];
    const float* bgc   = (const float*)d_in[5];
    const float* fc2_w = (const float*)d_in[6];
    const float* fc2_b = (const float*)d_in[7];
    const int*   src   = (const int*)d_in[8];
    const int*   dst   = (const int*)d_in[9];
    float* out = (float*)d_out;

    char* p = (char*)d_ws;
    auto alloc = [&](size_t bytes) {
        char* r = p;
        p += (bytes + 255) & ~(size_t)255;
        return r;
    };
    int*   chunk_dst = (int*)alloc((size_t)N_CHUNKS * HIST_WORDS * 4);
    int*   chunk_src = (int*)alloc((size_t)N_CHUNKS * HIST_WORDS * 4);
    int*   base32    = (int*)alloc((size_t)N_CHUNKS * N_NODES * 4);
    unsigned char* lrank8 = (unsigned char*)alloc((size_t)N_EDGES);
    float* rsq_in  = (float*)alloc((size_t)N_NODES * 4);
    float* rsq_out = (float*)alloc((size_t)N_NODES * 4);
    float* sq_out  = (float*)alloc((size_t)N_NODES * 4);
    int*   row_ptr   = (int*)alloc((size_t)(N_NODES + 1) * 4);
    int*   row_local = (int*)alloc((size_t)N_NODES * 4);
    int*   blk_sum   = (int*)alloc((size_t)SCAN_BLKS * 4);
    unsigned short* col16 = (unsigned short*)alloc((size_t)N_EDGES * 2);
    unsigned short* h0b  = (unsigned short*)alloc((size_t)N_NODES * H_F * 2);
    unsigned short* h0s  = (unsigned short*)alloc((size_t)N_NODES * H_F * 2);
    unsigned short* hAs  = (unsigned short*)alloc((size_t)N_NODES * H_F * 2);
    unsigned short* hBs  = (unsigned short*)alloc((size_t)N_NODES * H_F * 2);
    short* fc1_wT  = (short*)alloc((size_t)128 * 256 * 2);
    short* WcatT   = (short*)alloc((size_t)4 * 128 * 256 * 2);
    short* fc2_wT  = (short*)alloc((size_t)64 * 128 * 2);

    float beta[4], wscale[4], omb5[4];
    for (int l = 0; l < 4; l++) {
        beta[l] = (float)log(1.0 / (double)(l + 1) + 1.0);
        wscale[l] = 0.5f * beta[l];
        omb5[l] = 0.5f * (1.f - beta[l]);
    }

    prep_fc1w<<<128, 256, 0, stream>>>(fc1_w, fc1_wT);
    hist_fc1_prep<<<1265, 256, 0, stream>>>(src, dst, chunk_dst, chunk_src, lrank8,
                                            x, fc1_wT, fc1_b, h0b,
                                            W1, W2, fc2_w,
                                            wscale[0], wscale[1], wscale[2], wscale[3],
                                            WcatT, fc2_wT);
    scan1<<<SCAN_BLKS, 256, 0, stream>>>(chunk_dst, chunk_src, base32,
                                         rsq_in, rsq_out, sq_out, row_local, blk_sum);
    fill_fused<<<5157, 256, 0, stream>>>(src, dst, lrank8, base32, row_local, blk_sum,
                                         col16, row_ptr, h0b, rsq_out, h0s);

    const unsigned short* sp_in[4] = {h0s, hAs, hBs, hAs};
    unsigned short* out_b[4]       = {hAs, hBs, hAs, hBs};
    for (int l = 0; l < L_LAYERS; l++) {
        int last = (l == L_LAYERS - 1);
        layer_fused<<<N_NODES / 16, 256, 0, stream>>>(sp_in[l], h0b, row_ptr, col16,
                                                      rsq_in, rsq_out, sq_out,
                                                      WcatT + (size_t)l * 128 * 256,
                                                      bgc + (size_t)l * H_F,
                                                      omb5[l], out_b[l],
                                                      last ? fc2_wT : (const short*)nullptr,
                                                      last ? fc2_b : (const float*)nullptr,
                                                      last ? out : (float*)nullptr);
    }
}